// Round 5
// baseline (150.097 us; speedup 1.0000x reference)
//
#include <hip/hip_runtime.h>

// XCorrExt: B=32, S=160000, N=320, H=160, TAU=257, LAG_CUT=33
// out[b,f,tau-33] = 2*num/(e0 + e_tau + 1e-5), tau in [33,256]
// num[b,f,tau] = sum_n ext[tau+n]*frame[n]; frame[n] = xp[160f+n]
// ext[t] = xp[160f+t] (t<320) | xp[160f+t-160] (t>=320) | f=999,t>=320: x[t-320]
//
// R9: T=28->T=14 taus/lane restructure for true 8 waves/SIMD.
// R8 post-mortem: k-split landed VGPR=100 (live ~ 2T+44, T=28) -> still
// 4 waves/SIMD (512-reg pool), dispatch unchanged 81us, VALUBusy 69%.
// The 31% issue-idle needs more resident waves; that needs VGPR<=64;
// that needs T=14 (224 = 14 x 16 lanes). 14r breaks b128 quad alignment
// but 14r is always EVEN -> b64 window stream. Side win: r-stride 14
// mod 32 gives 16 DISTINCT even dword-banks per 16-lane group -> W-reads
// conflict-light (old quad-aligned layout was provably 8-way for any
// linear pad; R5/R6 XOR swizzles broke other streams and spilled).
// Geometry: NF=8 frames/block, 32 thr/frame (16 r x 2 halves), grid
// 125x32=4000 blocks, LDS 16.3KB. Live: acc14+W16+FQ8+misc ~ 55.

#define S_LEN 160000
#define FN    1000
#define NF    8
#define BLOCK 256
#define XSZ   (160 * (NF - 1) + 480)   // 1600 logical floats of signal
#define PHYS(i) ((i) + 4 * ((i) / 160))
#define TOFF  1640                     // > PHYS(XSZ-1)+3 = 1638, even
#define CBO   (TOFF + 264)             // 1904: combine buffer
#define CBSTR 17                       // odd stride -> spread banks
#define LDSZ  (CBO + CBSTR * 127 + 16) // 4079 -> round: 4080 floats = 16.3 KB

__global__ __launch_bounds__(BLOCK)
void xcorr_kernel(const float* __restrict__ x, float* __restrict__ out) {
    __shared__ __align__(16) float lds[LDSZ];
    const int tid   = threadIdx.x;
    const int b     = blockIdx.y;
    const int fbase = blockIdx.x * NF;
    const long bOff = (long)b * S_LEN;
    const int gbase = fbase * 160;

    // ---------------- stage shared X (coalesced float4, region-pad layout) ----
    for (int i = 4 * tid; i < XSZ; i += 4 * BLOCK) {
        const int gx = gbase + i;
        const int pa = PHYS(i);        // quads never cross a 160-region (4|160)
        if (gx + 3 < S_LEN) {
            *(float4*)&lds[pa] = *(const float4*)&x[bOff + gx];
        } else {
#pragma unroll
            for (int e = 0; e < 4; ++e)
                lds[pa + e] = (gx + e < S_LEN) ? x[bOff + gx + e] : 0.f;
        }
    }
    // T[j] = ext_{999}[320+j] = x[b, j]  (only the block containing f=999)
    if (fbase + NF > FN - 1) {
        for (int j = tid; j < 264; j += BLOCK)
            lds[TOFF + j] = x[bOff + j];
    }
    __syncthreads();

    // ---------------- compute ----------------
    const int h     = tid >> 5;        // frame slot 0..7
    const int half  = (tid >> 4) & 1;  // 0: n in [0,160), 1: n in [160,320)
    const int r     = tid & 15;        // tau lane 0..15
    const int f     = fbase + h;
    const bool useT = (f == FN - 1);
    const int tau0  = 33 + 14 * r;
    const int wb    = tau0 - 1;        // 32+14r, always EVEN (b64-aligned)
    const int xg    = 164 * h;         // region-padded frame base (160h + 4h)
    // ext addr = w + C, C selected by w-range (fold + region pad folded in):
    const int C0 = xg;                                // w in [0,160)
    const int C1 = xg + 4;                            // w in [160,320)
    const int C2 = useT ? (TOFF - 320) : (xg - 156);  // w in [320,480)
    const int C3 = useT ? (TOFF - 320) : (xg - 152);  // w in [480,580)
    const int k0 = 80 * half;          // 2-n step base (80 steps per half)

    float acc[14];
#pragma unroll
    for (int c = 0; c < 14; ++c) acc[c] = 0.f;
    float W[16];       // rotating window: ext[wb + m] at slot m & 15
    float FQ[2][4];    // rotating frame quad (distance-2-quad prefetch)

#pragma unroll
    for (int j = 0; j < 8; ++j) {      // window init: m in [160*half, +16)
        const int w = wb + 160 * half + 2 * j;
        const int cc = (w < 160) ? C0 : (w < 320) ? C1 : (w < 480) ? C2 : C3;
        const float2 q = *(const float2*)&lds[w + cc];
        W[2*j] = q.x; W[2*j+1] = q.y;
    }
#pragma unroll
    for (int j = 0; j < 2; ++j) {      // frame quads 40*half, 40*half+1
        const int fo = 160 * half + 4 * j;
        const float4 q = *(const float4*)&lds[xg + fo + ((fo >= 160) ? 4 : 0)];
        FQ[j][0] = q.x; FQ[j][1] = q.y; FQ[j][2] = q.z; FQ[j][3] = q.w;
    }

    float Tsum = 0.f, e0 = 0.f;

#pragma unroll 1
    for (int ko = 0; ko < 10; ++ko) {
#pragma unroll
        for (int ki = 0; ki < 8; ++ki) {
            const int k = k0 + ko * 8 + ki;   // k mod 8 == ki; n = 2k+d
#pragma unroll
            for (int d = 0; d < 2; ++d) {
                const float fv = FQ[(ki >> 1) & 1][2 * (ki & 1) + d];
#pragma unroll
                for (int c = 0; c < 14; ++c)
                    acc[c] = fmaf(fv, W[(1 + 2 * ki + d + c) & 15], acc[c]);
                const float tv = W[(1 + 2 * ki + d) & 15];   // ext[tau0+n]
                Tsum = fmaf(tv, tv, Tsum);                   // this half's slice
                e0   = fmaf(fv, fv, e0);                     // frame energy slice
            }
            // prefetch ext pair m = 2k+16,17 -> slots (2ki, 2ki+1)
            {
                const int w = wb + 2 * k + 16;
                const int cc = (w < 160) ? C0 : (w < 320) ? C1 : (w < 480) ? C2 : C3;
                const float2 q = *(const float2*)&lds[w + cc];
                W[(2*ki) & 15] = q.x; W[(2*ki + 1) & 15] = q.y;
            }
            // prefetch frame quad (k>>1)+2 on odd steps (slot parity (ki>>1)&1)
            if (ki & 1) {
                const int fo = 2 * k + 6;     // = 4*((k>>1)+2), k odd
                const int pad = ((fo >= 160) ? 4 : 0) + ((fo >= 320) ? 4 : 0);
                const float4 q = *(const float4*)&lds[xg + fo + pad];
                FQ[(ki >> 1) & 1][0] = q.x; FQ[(ki >> 1) & 1][1] = q.y;
                FQ[(ki >> 1) & 1][2] = q.z; FQ[(ki >> 1) & 1][3] = q.w;
            }
        }
    }

    // ---------------- combine halves: half0 -> LDS -> half1 adds --------------
    const int p = (h << 4) | r;        // pair index 0..127
    if (half == 0) {
#pragma unroll
        for (int j = 0; j < 14; ++j) lds[CBO + CBSTR * p + j] = acc[j];
        lds[CBO + CBSTR * p + 14] = e0;
        lds[CBO + CBSTR * p + 15] = Tsum;
    }
    __syncthreads();

    // ---------------- epilogue (half1 only): e_tau chain + normalize ----------
    // At half1 loop end, W[m&15] = ext[wb+m], m in [320,336)
    //   -> sv_c = ext[tau0+c+320] = W[(1+c)&15]  (c <= 12, in registers).
    // pv_c = ext[tau0+c]: 7 rolling b64 reads (w = wb+2j < 320).
    if (half == 1) {
#pragma unroll
        for (int j = 0; j < 14; ++j) acc[j] += lds[CBO + CBSTR * p + j];
        e0   += lds[CBO + CBSTR * p + 14];
        Tsum += lds[CBO + CBSTR * p + 15];

        float v[14];
#pragma unroll
        for (int j = 0; j < 7; ++j) {
            const int w = wb + 2 * j;            // <= 242+12 = 254 < 320
            const float2 q = *(const float2*)&lds[w + ((w < 160) ? C0 : C1)];
            v[2*j] = q.x; v[2*j+1] = q.y;
        }

        float* op = &out[((long)(b * FN + f)) * 224 + 14 * r];
        float et = Tsum;               // e_tau[tau0]
#pragma unroll
        for (int q = 0; q < 7; ++q) {
            float res[2];
#pragma unroll
            for (int e = 0; e < 2; ++e) {
                const int c = 2 * q + e;
                const float den = e0 + et + 1e-5f;
                res[e] = 2.f * acc[c] * __builtin_amdgcn_rcpf(den);
                if (c < 13) {
                    const float sv = W[(1 + c) & 15];   // ext[tau0+c+320]
                    const float pv = v[1 + c];          // ext[tau0+c]
                    et += sv * sv - pv * pv;
                }
            }
            *(float2*)&op[2 * q] = make_float2(res[0], res[1]);
        }
    }
}

extern "C" void kernel_launch(void* const* d_in, const int* in_sizes, int n_in,
                              void* d_out, int out_size, void* d_ws, size_t ws_size,
                              hipStream_t stream) {
    const float* x = (const float*)d_in[0];
    float* out = (float*)d_out;
    dim3 grid(FN / NF, 32);              // (125, 32) = 4000 blocks
    dim3 block(BLOCK);
    hipLaunchKernelGGL(xcorr_kernel, grid, block, 0, stream, x, out);
}

// Round 6
// 97.176 us; speedup vs baseline: 1.5446x; 1.5446x over previous
//
#include <hip/hip_runtime.h>

// XCorrExt: B=32, S=160000, N=320, H=160, TAU=257, LAG_CUT=33
// out[b,f,tau-33] = 2*num/(e0 + e_tau + 1e-5), tau in [33,256]
// num[b,f,tau] = sum_n ext[tau+n]*frame[n]; frame[n] = xp[160f+n]
// ext[t] = xp[160f+t] (t<320) | xp[160f+t-160] (t>=320) | f=999,t>=320: x[t-320]
//
// R10: MFMA reformulation. R9 showed scalar-fp32 path is issue-bound
// (time ~ instruction count; floor ~70us). Move num to the matrix pipe:
// per frame a 16x16x544 GEMM (Toeplitz embedding):
//   C[t1][t0] = sum_j A[t1,j]*B[j,t0], tau = 33+16*t1+t0 (rows 14,15 dropped)
//   A[t1,j] = fr[j-16t1] (zero outside [0,320); 8-blocks all-in/out -> addr cndmask)
//   B[j,t0] = ext[33+t0+j] (Hankel)
// 17 K-steps of v_mfma_f32_16x16x32_f16, one wave per frame, fp32 acc.
// Energies exact-fp32 via block prefix-sum of s^2 (csg); f=999 tail via csT.
// Hankel B is 2B-misaligned -> store ext TWICE (natural cE + 1-half-shifted
// cO); every lane then reads 4 dword-aligned dwords (ds_read2-able).
// A-frag b128 reads are 16B-aligned and bank-BALANCED (8 dwords/bank exact).
// fp16 error ~8e-5 on xcorr (<< passing 3.9e-3); denominators stay fp32.

typedef _Float16 f16;
typedef _Float16 h8 __attribute__((ext_vector_type(8)));
typedef _Float16 h4 __attribute__((ext_vector_type(4)));
typedef float    f4 __attribute__((ext_vector_type(4)));

#define S_LEN 160000
#define FN    1000
#define NF    8
#define BLOCK 256
#define USZ   1536              // staged signal floats: 160*(NF-1)+416

// smem byte offsets (all 16B-aligned)
#define ZPAD_OFF 0              // 16B zeros (A-frag OOB target; cO c=0 guard)
#define CE_OFF   16             // copyE: [8][592] f16 (ext natural)
#define CO_OFF   9488           // copyO: [8][600] f16 (ext shifted +1 half)
#define SH_OFF   19088          // s_h:   f16[1544]
#define TH_OFF   22176          // T_h:   f16[272]
#define CSG_OFF  22720          // csg:   float[1544] (excl. prefix of s^2)
#define CST_OFF  28896          // csT:   float[260]
#define TOT_OFF  29936          // tot:   float[256]  (scan scratch)
#define SMEM_SZ  30960

__global__ __launch_bounds__(BLOCK)
void xcorr_kernel(const float* __restrict__ x, float* __restrict__ out) {
    __shared__ __align__(16) unsigned char smem[SMEM_SZ];
    f16*   zpad = (f16*)(smem + ZPAD_OFF);
    f16*   cE   = (f16*)(smem + CE_OFF);
    f16*   cO   = (f16*)(smem + CO_OFF);
    f16*   s_h  = (f16*)(smem + SH_OFF);
    f16*   T_h  = (f16*)(smem + TH_OFF);
    float* csg  = (float*)(smem + CSG_OFF);
    float* csT  = (float*)(smem + CST_OFF);
    float* tot  = (float*)(smem + TOT_OFF);

    const int tid   = threadIdx.x;
    const int b     = blockIdx.y;
    const int fbase = blockIdx.x * NF;
    const long bOff = (long)b * S_LEN;
    const int gbase = fbase * 160;
    const bool lastBlk = (fbase + NF >= FN);

    // ---------------- P1: stage s_h (f16) + raw squares into csg --------------
    for (int i = 4*tid; i < USZ; i += 4*BLOCK) {
        const int gx = gbase + i;
        float v0, v1, v2, v3;
        if (gx + 3 < S_LEN) {
            const float4 v = *(const float4*)&x[bOff + gx];
            v0 = v.x; v1 = v.y; v2 = v.z; v3 = v.w;
        } else {
            v0 = (gx+0 < S_LEN) ? x[bOff+gx+0] : 0.f;
            v1 = (gx+1 < S_LEN) ? x[bOff+gx+1] : 0.f;
            v2 = (gx+2 < S_LEN) ? x[bOff+gx+2] : 0.f;
            v3 = (gx+3 < S_LEN) ? x[bOff+gx+3] : 0.f;
        }
        h4 hv; hv[0]=(f16)v0; hv[1]=(f16)v1; hv[2]=(f16)v2; hv[3]=(f16)v3;
        *(h4*)&s_h[i] = hv;
        f4 sq; sq[0]=v0*v0; sq[1]=v1*v1; sq[2]=v2*v2; sq[3]=v3*v3;
        *(f4*)&csg[i] = sq;
    }
    if (tid < 8) { csg[USZ + tid] = 0.f; s_h[USZ + tid] = (f16)0.f; }
    if (tid == 0) { uint4 z; z.x=z.y=z.z=z.w=0u; *(uint4*)(smem + ZPAD_OFF) = z; }
    if (lastBlk) {
        for (int j = tid; j < 264; j += BLOCK) {
            const float tv = (j < 256) ? x[bOff + j] : 0.f;
            T_h[j] = (f16)tv;
            if (j < 260) csT[j] = tv * tv;
        }
    }
    __syncthreads();

    // ---------------- P2: build copyE; csg per-thread local prefix ------------
    for (int idx = tid; idx < NF*74; idx += BLOCK) {
        const int fi = idx / 74;
        const int t  = 8 * (idx - 74*fi);       // 0..584
        h8 v;
        if (t >= 576) {
            union { unsigned u[4]; h8 h; } Z;
            Z.u[0]=Z.u[1]=Z.u[2]=Z.u[3]=0u; v = Z.h;   // zero pad [576,592)
        } else {
            const f16* src;
            if (lastBlk && (fbase + fi == FN-1) && t >= 320) src = &T_h[t-320];
            else src = &s_h[160*fi + t - ((t >= 320) ? 160 : 0)];
            v = *(const h8*)src;                // 16B-aligned (t mult of 8)
        }
        *(h8*)&cE[fi*592 + t] = v;
    }
    float p[7]; float mytot = 0.f;
    {
        const int t0 = 7*tid;
#pragma unroll
        for (int e = 0; e < 7; ++e) {
            const float r = (t0+e < 1544) ? csg[t0+e] : 0.f;
            p[e] = mytot;                       // exclusive within thread
            mytot += r;
        }
        tot[tid] = mytot;
    }
    __syncthreads();

    // ---------------- P3: wave0 scans (tot, csT); waves1-3 build copyO --------
    if (tid < 64) {
        float t0 = tot[4*tid+0], t1 = tot[4*tid+1], t2 = tot[4*tid+2], t3 = tot[4*tid+3];
        const float s1 = t0, s2 = t0+t1, s3 = t0+t1+t2, tt = t0+t1+t2+t3;
        float sc = tt;
#pragma unroll
        for (int d = 1; d < 64; d <<= 1) {
            const float o = __shfl_up(sc, d);
            sc += (tid >= d) ? o : 0.f;
        }
        const float base = sc - tt;             // exclusive across lanes
        tot[4*tid+0] = base;
        tot[4*tid+1] = base + s1;
        tot[4*tid+2] = base + s2;
        tot[4*tid+3] = base + s3;
        if (lastBlk) {                          // exclusive scan of csT (260)
            float r[5]; float mt = 0.f;
#pragma unroll
            for (int e = 0; e < 5; ++e) {
                const int j = 5*tid + e;
                const float rv = (j < 260) ? csT[j] : 0.f;
                r[e] = mt; mt += rv;
            }
            float sc2 = mt;
#pragma unroll
            for (int d = 1; d < 64; d <<= 1) {
                const float o = __shfl_up(sc2, d);
                sc2 += (tid >= d) ? o : 0.f;
            }
            const float b2 = sc2 - mt;
#pragma unroll
            for (int e = 0; e < 5; ++e) {
                const int j = 5*tid + e;
                if (j < 260) csT[j] = b2 + r[e];
            }
        }
    } else {
        // copyO dword d = halves (ext[2d-1], ext[2d]) via alignbit on cE dwords
        for (int idx = tid - 64; idx < NF*75; idx += (BLOCK-64)) {
            const int fi = idx / 75;
            const int c  = idx - 75*fi;         // dword chunk [4c, 4c+4)
            const unsigned* Edw = (const unsigned*)&cE[fi*592];
            const uint4 lo4 = *(const uint4*)(Edw + 4*c - 4);  // c=0 -> zpad
            const uint4 hi4 = *(const uint4*)(Edw + 4*c);
            uint4 o;
            o.x = __builtin_amdgcn_alignbit(hi4.x, lo4.w, 16);
            o.y = __builtin_amdgcn_alignbit(hi4.y, hi4.x, 16);
            o.z = __builtin_amdgcn_alignbit(hi4.z, hi4.y, 16);
            o.w = __builtin_amdgcn_alignbit(hi4.w, hi4.z, 16);
            *(uint4*)((unsigned*)&cO[fi*600] + 4*c) = o;
        }
    }
    __syncthreads();

    // ---------------- P4: apply csg bases (exclusive prefix complete) ---------
    {
        const float base = tot[tid];
        const int t0 = 7*tid;
#pragma unroll
        for (int e = 0; e < 7; ++e)
            if (t0+e < 1544) csg[t0+e] = base + p[e];
    }
    __syncthreads();

    // ---------------- compute: wave w -> frames 2w, 2w+1 ----------------------
    const int lane = tid & 63;
    const int w    = tid >> 6;
    const int col  = lane & 15;          // A-row t1-lane, B-col t0, C-col
    const int q    = lane >> 4;          // k-group; C-row = 4q+v
    const int off0 = 8*q - 16*col;       // A: off = j - 16*row, j = 32s+8q
    const int tb0  = 33 + col + 8*q;     // B: half index base into ext

    for (int ff = 0; ff < 2; ++ff) {
        const int fi = 2*w + ff;
        const int f  = fbase + fi;
        const f16* eE = cE + fi*592;
        const unsigned* bptr = (tb0 & 1)
            ? ((const unsigned*)(cO + fi*600) + ((tb0 + 1) >> 1))
            : ((const unsigned*)eE + (tb0 >> 1));
        f4 acc = {0.f, 0.f, 0.f, 0.f};
#pragma unroll
        for (int s = 0; s < 17; ++s) {
            const int off = off0 + 32*s;
            const f16* ap = ((unsigned)off <= 312u) ? (eE + off) : zpad;
            const h8 a = *(const h8*)ap;               // ds_read_b128, aligned
            union { unsigned u[4]; h8 h; } B;
            B.u[0] = bptr[16*s + 0];
            B.u[1] = bptr[16*s + 1];
            B.u[2] = bptr[16*s + 2];
            B.u[3] = bptr[16*s + 3];
            acc = __builtin_amdgcn_mfma_f32_16x16x32_f16(a, B.h, acc, 0, 0, 0);
        }
        // epilogue: energies from exact-fp32 prefix sums
        const int D = 160*fi;
        const float c0   = csg[D];
        const float c160 = csg[D+160];
        const float c320 = csg[D+320];
        const float e0   = c320 - c0;
        const bool isLast = (f == FN-1);
        float* op = &out[(long)(b*FN + f) * 224];
#pragma unroll
        for (int v = 0; v < 4; ++v) {
            const int t1 = 4*q + v;
            if (t1 <= 13) {
                const int tau = 33 + 16*t1 + col;
                const float et = isLast
                    ? (c320 - csg[D+tau] + csT[tau])
                    : (c320 - csg[D+tau] - c160 + csg[D+160+tau]);
                const float den = e0 + et + 1e-5f;
                op[tau - 33] = 2.f * acc[v] * __builtin_amdgcn_rcpf(den);
            }
        }
    }
}

extern "C" void kernel_launch(void* const* d_in, const int* in_sizes, int n_in,
                              void* d_out, int out_size, void* d_ws, size_t ws_size,
                              hipStream_t stream) {
    const float* x = (const float*)d_in[0];
    float* out = (float*)d_out;
    dim3 grid(FN / NF, 32);              // (125, 32) = 4000 blocks
    dim3 block(BLOCK);
    hipLaunchKernelGGL(xcorr_kernel, grid, block, 0, stream, x, out);
}

// Round 8
// 91.003 us; speedup vs baseline: 1.6494x; 1.0678x over previous
//
#include <hip/hip_runtime.h>

// XCorrExt: B=32, S=160000, N=320, H=160, TAU=257, LAG_CUT=33
// out[b,f,tau-33] = 2*num/(e0 + e_tau + 1e-5), tau in [33,256]
// num[b,f,tau] = sum_n ext[tau+n]*frame[n]; frame[n] = xp[160f+n]
// ext[t] = xp[160f+t] (t<320) | xp[160f+t-160] (t>=320) | f=999,t>=320: x[t-320]
//
// R12 = R11 + fold-straddle fix. R11 failed (absmax 8.7e-2): the B-fragment
// covers 8 halves [tb0+32s, +8); selecting pA/pB by the START index breaks
// when the group straddles the t=320 ext-fold (start in [313,319] -- only
// possible at s==8, for lanes tb0 in [57,63]). Fix: per-frame BRIDGE copy
// of ext[304..336) (32 halves brE + 16 shifted dwords brO, 1KB LDS), and a
// per-lane precomputed s=8 pointer p8 = pA | bridge | pB by tb0 range. The
// step select becomes static (s<8 -> pA, s==8 -> p8, s>8 -> pB), deleting
// the 17 runtime compares too.
// R11 recap: 16x16x544 Toeplitz GEMM/frame (mfma_f32_16x16x32_f16), A reads
// s_h directly (b128-aligned), B reads s_h/sO (block-wide shifted copy) with
// fold by pointer, exact-fp32 energies via hierarchical block prefix sum.
// LDS 16.4KB -> 8 blocks/CU (32 waves).

typedef _Float16 f16;
typedef _Float16 h8 __attribute__((ext_vector_type(8)));
typedef _Float16 h4 __attribute__((ext_vector_type(4)));
typedef float    f4 __attribute__((ext_vector_type(4)));

#define S_LEN 160000
#define FN    1000
#define NF    8
#define BLOCK 256
#define USZ   1536              // staged signal floats: 160*(NF-1)+416

// smem byte offsets (all 16B-aligned)
#define ZPAD_OFF 0              // 16B zeros (A-frag OOB target)
#define SE_OFF   16             // s_h: f16[1568] (zero pad [1536,1568))
#define SO_OFF   3152           // sO:  dword[784], dw j = halves (2j-1, 2j)
#define TH_OFF   6288           // T_h: f16[288] (zero pad [256,288))
#define TO_OFF   6864           // TO:  dword[144]
#define BRE_OFF  7440           // brE: f16[8][32]  = ext[304..336) per frame
#define BRO_OFF  7952           // brO: dword[8][16], dw j = ext halves (303+2j, 304+2j)
#define CSG_OFF  8464           // csg: float[1552] (excl. prefix of s^2)
#define CST_OFF  14672          // csT: float[260]
#define TOT_OFF  15712          // tot: float[260] (256 + wave sums)
#define SMEM_SZ  16752

__global__ __launch_bounds__(BLOCK)
void xcorr_kernel(const float* __restrict__ x, float* __restrict__ out) {
    __shared__ __align__(16) unsigned char smem[SMEM_SZ];
    f16*      zpad = (f16*)(smem + ZPAD_OFF);
    f16*      s_h  = (f16*)(smem + SE_OFF);
    unsigned* sOd  = (unsigned*)(smem + SO_OFF);
    f16*      T_h  = (f16*)(smem + TH_OFF);
    unsigned* TOd  = (unsigned*)(smem + TO_OFF);
    f16*      brE  = (f16*)(smem + BRE_OFF);
    unsigned* brOd = (unsigned*)(smem + BRO_OFF);
    float*    csg  = (float*)(smem + CSG_OFF);
    float*    csT  = (float*)(smem + CST_OFF);
    float*    tot  = (float*)(smem + TOT_OFF);

    const int tid   = threadIdx.x;
    const int b     = blockIdx.y;
    const int fbase = blockIdx.x * NF;
    const long bOff = (long)b * S_LEN;
    const int gbase = fbase * 160;
    const bool lastBlk = (fbase + NF >= FN);

    // ---------------- P1: stage s_h (f16) + raw squares into csg --------------
    for (int i = 4*tid; i < USZ; i += 4*BLOCK) {
        const int gx = gbase + i;
        float v0, v1, v2, v3;
        if (gx + 3 < S_LEN) {
            const float4 v = *(const float4*)&x[bOff + gx];
            v0 = v.x; v1 = v.y; v2 = v.z; v3 = v.w;
        } else {
            v0 = (gx+0 < S_LEN) ? x[bOff+gx+0] : 0.f;
            v1 = (gx+1 < S_LEN) ? x[bOff+gx+1] : 0.f;
            v2 = (gx+2 < S_LEN) ? x[bOff+gx+2] : 0.f;
            v3 = (gx+3 < S_LEN) ? x[bOff+gx+3] : 0.f;
        }
        h4 hv; hv[0]=(f16)v0; hv[1]=(f16)v1; hv[2]=(f16)v2; hv[3]=(f16)v3;
        *(h4*)&s_h[i] = hv;
        f4 sq; sq[0]=v0*v0; sq[1]=v1*v1; sq[2]=v2*v2; sq[3]=v3*v3;
        *(f4*)&csg[i] = sq;
    }
    if (tid < 8) {                       // zero pad halves [1536,1568)
        h4 z; z[0]=(f16)0.f; z[1]=(f16)0.f; z[2]=(f16)0.f; z[3]=(f16)0.f;
        *(h4*)&s_h[1536 + 4*tid] = z;
    }
    if (tid < 16) csg[1536 + tid] = 0.f;
    if (tid == 0) { uint4 z; z.x=z.y=z.z=z.w=0u; *(uint4*)(smem + ZPAD_OFF) = z; }
    if (lastBlk) {
        for (int j = tid; j < 288; j += BLOCK) {
            const float tv = (j < 256) ? x[bOff + j] : 0.f;
            T_h[j] = (f16)tv;
            if (j < 260) csT[j] = tv * tv;
        }
    }
    __syncthreads();

    // ---------------- P2: build sO (+TO) + bridge; csg local prefix -----------
    {
        const unsigned* sEd = (const unsigned*)s_h;     // 784 dwords
        for (int idx = tid; idx < 196; idx += BLOCK) {
            uint4 lo4;
            if (idx) lo4 = *(const uint4*)(sEd + 4*idx - 4);
            else     { lo4.x=lo4.y=lo4.z=0u; lo4.w=0u; }
            const uint4 hi4 = *(const uint4*)(sEd + 4*idx);
            uint4 o;
            o.x = __builtin_amdgcn_alignbit(hi4.x, lo4.w, 16);
            o.y = __builtin_amdgcn_alignbit(hi4.y, hi4.x, 16);
            o.z = __builtin_amdgcn_alignbit(hi4.z, hi4.y, 16);
            o.w = __builtin_amdgcn_alignbit(hi4.w, hi4.z, 16);
            *(uint4*)(sOd + 4*idx) = o;
        }
        if (lastBlk) {
            const unsigned* THd = (const unsigned*)T_h; // 144 dwords
            for (int idx = tid; idx < 36; idx += BLOCK) {
                uint4 lo4;
                if (idx) lo4 = *(const uint4*)(THd + 4*idx - 4);
                else     { lo4.x=lo4.y=lo4.z=0u; lo4.w=0u; }
                const uint4 hi4 = *(const uint4*)(THd + 4*idx);
                uint4 o;
                o.x = __builtin_amdgcn_alignbit(hi4.x, lo4.w, 16);
                o.y = __builtin_amdgcn_alignbit(hi4.y, hi4.x, 16);
                o.z = __builtin_amdgcn_alignbit(hi4.z, hi4.y, 16);
                o.w = __builtin_amdgcn_alignbit(hi4.w, hi4.z, 16);
                *(uint4*)(TOd + 4*idx) = o;
            }
        }
        // bridge: ext[304..336) per frame (contiguous across the t=320 fold)
        {
            const int fi = tid >> 5, j = tid & 31;      // 256 threads exactly
            const int t = 304 + j;
            const bool lastF = lastBlk && (fbase + fi == FN-1);
            f16 v;
            if (t < 320)      v = s_h[160*fi + t];
            else if (lastF)   v = T_h[t - 320];
            else              v = s_h[160*fi + t - 160];
            brE[32*fi + j] = v;
        }
        if (tid < NF*16) {                              // 128 threads
            const int fi = tid >> 4, j = tid & 15;
            const int tl = 303 + 2*j, th = 304 + 2*j;
            const bool lastF = lastBlk && (fbase + fi == FN-1);
            const f16 lo = (tl < 320) ? s_h[160*fi + tl]
                          : (lastF ? T_h[tl-320] : s_h[160*fi + tl - 160]);
            const f16 hi = (th < 320) ? s_h[160*fi + th]
                          : (lastF ? T_h[th-320] : s_h[160*fi + th - 160]);
            union { struct { f16 a, c; } h; unsigned u; } pk;
            pk.h.a = lo; pk.h.c = hi;
            brOd[16*fi + j] = pk.u;
        }
    }
    float p[7]; float mytot = 0.f;
    {
        const int t0 = 7*tid;
#pragma unroll
        for (int e = 0; e < 7; ++e) {
            const float r = (t0+e < 1552) ? csg[t0+e] : 0.f;
            p[e] = mytot;                       // exclusive within thread
            mytot += r;
        }
        tot[tid] = mytot;
    }
    __syncthreads();

    // ---------------- P3: all-wave scan (wave-local shfl + wave totals) -------
    const int lane = tid & 63;
    const int wv   = tid >> 6;
    {
        const float v = tot[tid];
        float sc = v;
#pragma unroll
        for (int d = 1; d < 64; d <<= 1) {
            const float o = __shfl_up(sc, d);
            sc += (lane >= d) ? o : 0.f;
        }
        tot[tid] = sc - v;                      // exclusive within wave
        if (lane == 63) tot[256 + wv] = sc;     // wave total
        if (lastBlk && wv == 0) {               // exclusive scan of csT (260)
            float r[5]; float mt = 0.f;
#pragma unroll
            for (int e = 0; e < 5; ++e) {
                const int j = 5*lane + e;
                const float rv = (j < 260) ? csT[j] : 0.f;
                r[e] = mt; mt += rv;
            }
            float sc2 = mt;
#pragma unroll
            for (int d = 1; d < 64; d <<= 1) {
                const float o = __shfl_up(sc2, d);
                sc2 += (lane >= d) ? o : 0.f;
            }
            const float b2 = sc2 - mt;
#pragma unroll
            for (int e = 0; e < 5; ++e) {
                const int j = 5*lane + e;
                if (j < 260) csT[j] = b2 + r[e];
            }
        }
    }
    __syncthreads();

    // ---------------- P4: apply csg bases (exclusive prefix complete) ---------
    {
        const float w1 = tot[256], w2 = tot[257], w3 = tot[258];
        const float wbase = ((wv > 0) ? w1 : 0.f) + ((wv > 1) ? w2 : 0.f)
                          + ((wv > 2) ? w3 : 0.f);
        const float base = wbase + tot[tid];
        const int t0 = 7*tid;
#pragma unroll
        for (int e = 0; e < 7; ++e)
            if (t0+e < 1552) csg[t0+e] = base + p[e];
    }
    __syncthreads();

    // ---------------- compute: wave wv -> frames 2wv, 2wv+1 -------------------
    const int col  = lane & 15;          // A-row t1-lane, B-col t0, C-col
    const int q    = lane >> 4;          // k-group; C-row = 4q+v
    const int off0 = 8*q - 16*col;       // A: off = j - 16*row, j = 32s+8q
    const int tb0  = 33 + col + 8*q;     // B: half index base into ext, [33,72]
    const int pc   = tb0 & 1;
    const unsigned* bbS = pc ? sOd : (const unsigned*)s_h;
    const unsigned* bbT = pc ? TOd : (const unsigned*)T_h;

#pragma unroll 1
    for (int ff = 0; ff < 2; ++ff) {
        const int fi = 2*wv + ff;
        const int f  = fbase + fi;
        const bool isLast = (f == FN-1);
        const f16* frame = s_h + 160*fi;
        const int i0 = (160*fi + tb0 + pc) >> 1;
        const unsigned* pA = bbS + i0;                       // group all t<320
        const unsigned* pB = isLast ? (bbT + ((tb0 - 320 + pc) >> 1))
                                    : (bbS + (i0 - 80));     // group all t>=320
        // s=8 pointer: group start tb0+256. <=312 -> pA; 313..319 -> bridge;
        // >=320 -> pB. Bridge base ext[304): dword off (tb0-48+pc)>>1.
        const unsigned* brB = pc ? (brOd + 16*fi) : ((const unsigned*)brE + 16*fi);
        const unsigned* p8 = (tb0 <= 56) ? pA
                           : ((tb0 <= 63) ? (brB + ((tb0 - 48 + pc) >> 1) - 128)
                                          : pB);
        f4 acc = {0.f, 0.f, 0.f, 0.f};
#pragma unroll
        for (int s = 0; s < 17; ++s) {
            const int off = off0 + 32*s;
            const f16* ap = ((unsigned)off <= 312u) ? (frame + off) : zpad;
            const h8 a = *(const h8*)ap;                     // aligned b128
            const unsigned* bp = (s < 8) ? pA : ((s == 8) ? p8 : pB);
            union { unsigned u[4]; h8 h; } Bf;
            Bf.u[0] = bp[16*s + 0];
            Bf.u[1] = bp[16*s + 1];
            Bf.u[2] = bp[16*s + 2];
            Bf.u[3] = bp[16*s + 3];
            acc = __builtin_amdgcn_mfma_f32_16x16x32_f16(a, Bf.h, acc, 0, 0, 0);
        }
        // epilogue: energies from exact-fp32 prefix sums
        const int D = 160*fi;
        const float c0   = csg[D];
        const float c160 = csg[D+160];
        const float c320 = csg[D+320];
        const float e0   = c320 - c0;
        float* op = &out[(long)(b*FN + f) * 224];
#pragma unroll
        for (int v = 0; v < 4; ++v) {
            const int t1 = 4*q + v;
            if (t1 <= 13) {
                const int tau = 33 + 16*t1 + col;
                const float et = isLast
                    ? (c320 - csg[D+tau] + csT[tau])
                    : (c320 - csg[D+tau] - c160 + csg[D+160+tau]);
                const float den = e0 + et + 1e-5f;
                op[tau - 33] = 2.f * acc[v] * __builtin_amdgcn_rcpf(den);
            }
        }
    }
}

extern "C" void kernel_launch(void* const* d_in, const int* in_sizes, int n_in,
                              void* d_out, int out_size, void* d_ws, size_t ws_size,
                              hipStream_t stream) {
    const float* x = (const float*)d_in[0];
    float* out = (float*)d_out;
    dim3 grid(FN / NF, 32);              // (125, 32) = 4000 blocks
    dim3 block(BLOCK);
    hipLaunchKernelGGL(xcorr_kernel, grid, block, 0, stream, x, out);
}